// Round 1
// baseline (136.250 us; speedup 1.0000x reference)
//
#include <hip/hip_runtime.h>

#define B_   4
#define FIN  64
#define FOUT 64
#define HI   128
#define WI   128
#define HO   126
#define WO   126
#define TILE 16
#define OCH  16
#define IN_T 18   // TILE + 2 (3x3 VALID halo)

__global__ __launch_bounds__(256, 4) void fused_dwconv_combine(
    const float* __restrict__ x,  const float* __restrict__ Wf,
    const float* __restrict__ bf, const float* __restrict__ Wc,
    const float* __restrict__ bc, float* __restrict__ out)
{
    // double-buffered input tile; pad row to 20 floats to soften bank aliasing
    __shared__ float xs[2][IN_T][IN_T + 2];

    const int tid = threadIdx.x;
    const int tx  = tid & (TILE - 1);
    const int ty  = tid >> 4;
    const int tileId = blockIdx.x;        // 0..63 spatial tiles (8x8)
    const int tX = tileId & 7, tY = tileId >> 3;
    const int o0 = blockIdx.y * OCH;      // output-channel chunk
    const int b  = blockIdx.z;

    const int ho = tY * TILE + ty;
    const int wo = tX * TILE + tx;

    const float* xb = x + (size_t)b * FIN * HI * WI;

    auto stage = [&](int i, int buf) {
        const float* xp = xb + (size_t)i * HI * WI;
        int e = tid;                       // first 256 elements
        {
            int r = e / IN_T, c = e - r * IN_T;
            int gy = min(tY * TILE + r, HI - 1);
            int gx = min(tX * TILE + c, WI - 1);
            xs[buf][r][c] = xp[gy * WI + gx];
        }
        e = tid + 256;                     // remaining 68 elements
        if (e < IN_T * IN_T) {
            int r = e / IN_T, c = e - r * IN_T;
            int gy = min(tY * TILE + r, HI - 1);
            int gx = min(tX * TILE + c, WI - 1);
            xs[buf][r][c] = xp[gy * WI + gx];
        }
    };

    float acc[OCH];
#pragma unroll
    for (int oo = 0; oo < OCH; ++oo) acc[oo] = bc[o0 + oo];

    stage(0, 0);

    for (int i = 0; i < FIN; ++i) {
        __syncthreads();                   // stage(i) visible; prev reads done
        if (i + 1 < FIN) stage(i + 1, (i + 1) & 1);
        const int cur = i & 1;

        float win[9];
#pragma unroll
        for (int dy = 0; dy < 3; ++dy)
#pragma unroll
            for (int dx = 0; dx < 3; ++dx)
                win[dy * 3 + dx] = xs[cur][ty + dy][tx + dx];

#pragma unroll
        for (int oo = 0; oo < OCH; ++oo) {
            const int o = o0 + oo;
            const float* wp = Wf + ((size_t)o * FIN + i) * 9;  // wave-uniform -> s_load
            float s = bf[o * FIN + i];
#pragma unroll
            for (int t = 0; t < 9; ++t) s = fmaf(wp[t], win[t], s);
            s = fmaxf(s, 0.0f);
            acc[oo] = fmaf(Wc[o * FIN + i], s, acc[oo]);
        }
    }

    if (ho < HO && wo < WO) {
        size_t base = ((size_t)b * FOUT + o0) * (size_t)(HO * WO)
                    + (size_t)ho * WO + wo;
#pragma unroll
        for (int oo = 0; oo < OCH; ++oo)
            out[base + (size_t)oo * (HO * WO)] = acc[oo];
    }
}

extern "C" void kernel_launch(void* const* d_in, const int* in_sizes, int n_in,
                              void* d_out, int out_size, void* d_ws, size_t ws_size,
                              hipStream_t stream) {
    const float* x  = (const float*)d_in[0];
    const float* Wf = (const float*)d_in[1];
    const float* bf = (const float*)d_in[2];
    const float* Wc = (const float*)d_in[3];
    const float* bc = (const float*)d_in[4];
    float* out = (float*)d_out;

    dim3 grid(64, FOUT / OCH, B_);   // 8x8 spatial tiles, 4 o-chunks, 4 batches
    hipLaunchKernelGGL(fused_dwconv_combine, grid, dim3(256), 0, stream,
                       x, Wf, bf, Wc, bc, out);
}

// Round 2
// 121.002 us; speedup vs baseline: 1.1260x; 1.1260x over previous
//
#include <hip/hip_runtime.h>

#define FIN  64
#define FOUT 64
#define HI   128
#define WI   128
#define HO   126
#define WO   126
#define TH   16      // output tile rows per block
#define TW   64      // output tile cols per block
#define PX   4       // pixels per thread (1x4 strip)
#define OCH  8       // output channels per block
#define HR   18      // halo rows  (TH+2)
#define HC   66      // halo cols  (TW+2)
#define LSTR 68      // padded LDS row stride (17 float4s -> 16B-aligned rows)
#define NSTAGE 5     // ceil(HR*HC / 256)

__global__ __launch_bounds__(256, 2) void fused_dwconv_combine(
    const float* __restrict__ x,  const float* __restrict__ Wf,
    const float* __restrict__ bf, const float* __restrict__ Wc,
    const float* __restrict__ bc, float* __restrict__ out)
{
    __shared__ float xs[2][HR * LSTR];

    const int tid = threadIdx.x;
    const int tx  = tid & 15;       // 0..15 -> output cols 4tx..4tx+3
    const int ty  = tid >> 4;       // 0..15 -> output row
    const int tY  = blockIdx.x >> 1;    // 0..7 spatial row tile
    const int tX  = blockIdx.x & 1;     // 0..1 spatial col tile
    const int o0  = blockIdx.y * OCH;
    const int b   = blockIdx.z;

    const int row0 = tY * TH;
    const int col0 = tX * TW;

    // staging map (computed ONCE; only channel base changes per i)
    int goff[NSTAGE], loff[NSTAGE];
#pragma unroll
    for (int k = 0; k < NSTAGE; ++k) {
        int e = tid + k * 256;
        if (e < HR * HC) {
            int r = e / HC, c = e - r * HC;
            int gy = min(row0 + r, HI - 1);
            int gx = min(col0 + c, WI - 1);
            goff[k] = gy * WI + gx;
            loff[k] = r * LSTR + c;
        } else { goff[k] = 0; loff[k] = -1; }
    }

    const float* xb = x + (size_t)b * FIN * HI * WI;

    float acc[OCH][PX];
#pragma unroll
    for (int oo = 0; oo < OCH; ++oo) {
        float bcv = bc[o0 + oo];
#pragma unroll
        for (int p = 0; p < PX; ++p) acc[oo][p] = bcv;
    }

    // stage channel 0 into buffer 0
    {
        const float* xp = xb;
#pragma unroll
        for (int k = 0; k < NSTAGE; ++k)
            if (loff[k] >= 0) xs[0][loff[k]] = xp[goff[k]];
    }

    for (int i = 0; i < FIN; ++i) {
        const int cur = i & 1;

        // issue next-channel global loads into regs (latency hides under compute)
        float st[NSTAGE];
        if (i + 1 < FIN) {
            const float* xp = xb + (size_t)(i + 1) * (HI * WI);
#pragma unroll
            for (int k = 0; k < NSTAGE; ++k)
                if (loff[k] >= 0) st[k] = xp[goff[k]];
        }

        __syncthreads();   // xs[cur] writes (prev iter) visible; prev reads done

        // 3x6 window -> 18 regs (rows 16B-aligned: b128 + b64 merges)
        float win[3][6];
#pragma unroll
        for (int dy = 0; dy < 3; ++dy) {
            const float* rp = &xs[cur][(ty + dy) * LSTR + 4 * tx];
#pragma unroll
            for (int dx = 0; dx < 6; ++dx) win[dy][dx] = rp[dx];
        }

#pragma unroll
        for (int oo = 0; oo < OCH; ++oo) {
            const int o = o0 + oo;
            const float* wp = Wf + ((size_t)o * FIN + i) * 9;  // uniform -> s_load
            const float bfv = bf[o * FIN + i];
            const float wcv = Wc[o * FIN + i];
            float s0 = bfv, s1 = bfv, s2 = bfv, s3 = bfv;
#pragma unroll
            for (int dy = 0; dy < 3; ++dy)
#pragma unroll
                for (int dx = 0; dx < 3; ++dx) {
                    const float w = wp[dy * 3 + dx];
                    s0 = fmaf(w, win[dy][dx + 0], s0);
                    s1 = fmaf(w, win[dy][dx + 1], s1);
                    s2 = fmaf(w, win[dy][dx + 2], s2);
                    s3 = fmaf(w, win[dy][dx + 3], s3);
                }
            acc[oo][0] = fmaf(wcv, fmaxf(s0, 0.f), acc[oo][0]);
            acc[oo][1] = fmaf(wcv, fmaxf(s1, 0.f), acc[oo][1]);
            acc[oo][2] = fmaf(wcv, fmaxf(s2, 0.f), acc[oo][2]);
            acc[oo][3] = fmaf(wcv, fmaxf(s3, 0.f), acc[oo][3]);
        }

        // commit prefetched channel into the other buffer
        if (i + 1 < FIN) {
#pragma unroll
            for (int k = 0; k < NSTAGE; ++k)
                if (loff[k] >= 0) xs[cur ^ 1][loff[k]] = st[k];
        }
    }

    // epilogue: guarded scalar stores (4 px x 8 o)
    const int ho  = row0 + ty;
    const int wo0 = col0 + 4 * tx;
    if (ho < HO) {
#pragma unroll
        for (int oo = 0; oo < OCH; ++oo) {
            size_t base = ((size_t)b * FOUT + (o0 + oo)) * (size_t)(HO * WO)
                        + (size_t)ho * WO + wo0;
#pragma unroll
            for (int p = 0; p < PX; ++p)
                if (wo0 + p < WO) out[base + p] = acc[oo][p];
        }
    }
}

extern "C" void kernel_launch(void* const* d_in, const int* in_sizes, int n_in,
                              void* d_out, int out_size, void* d_ws, size_t ws_size,
                              hipStream_t stream) {
    const float* x  = (const float*)d_in[0];
    const float* Wf = (const float*)d_in[1];
    const float* bf = (const float*)d_in[2];
    const float* Wc = (const float*)d_in[3];
    const float* bc = (const float*)d_in[4];
    float* out = (float*)d_out;

    dim3 grid(16, FOUT / OCH, 4);   // 8x2 spatial tiles, 8 o-chunks, 4 batches
    hipLaunchKernelGGL(fused_dwconv_combine, grid, dim3(256), 0, stream,
                       x, Wf, bf, Wc, bc, out);
}